// Round 9
// baseline (606.189 us; speedup 1.0000x reference)
//
#include <hip/hip_runtime.h>

#define S_  2048
#define HD_ 64
#define NH_ 8
#define MARGIN 4e-3f

typedef _Float16 half8 __attribute__((ext_vector_type(8)));
typedef _Float16 half4v __attribute__((ext_vector_type(4)));
typedef float    f32x4 __attribute__((ext_vector_type(4)));

// 2nd smallest of 4 == 3rd largest counting multiplicity (matches top_k[-1] + >= semantics)
__device__ __forceinline__ float snd_smallest4(float a, float b, float c, float d){
  float lo1 = fminf(a,b), hi1 = fmaxf(a,b);
  float lo2 = fminf(c,d), hi2 = fmaxf(c,d);
  return fminf(fmaxf(lo1,lo2), fminf(hi1,hi2));
}

// exact fp32 dot, R3-validated summation order (d ascending, paired FMA chain)
// qrow is pre-scaled by 0.125 -> result = q.k/8
__device__ __forceinline__ float dot64(const float* __restrict__ qrow,
                                       const float* __restrict__ kcol){
  float acc = 0.f;
#pragma unroll
  for (int dp=0; dp<32; ++dp){
    float2 k2 = *(const float2*)(kcol + 2*dp);
    acc = fmaf(qrow[2*dp+1], k2.y, fmaf(qrow[2*dp], k2.x, acc));
  }
  return acc;
}

// =================== w_proj transpose + fp16 2-plane split: Wh/Wl[n][k] ===================
__global__ __launch_bounds__(256)
void wprep_kernel(const float* __restrict__ wproj,
                  _Float16* __restrict__ Wh, _Float16* __restrict__ Wl)
{
  __shared__ float t[64][65];
  const int k0 = (blockIdx.x >> 3) << 6;
  const int n0 = (blockIdx.x & 7) << 6;
  const int tx = threadIdx.x & 63, ty = threadIdx.x >> 6;
#pragma unroll
  for (int p=0;p<16;p++){
    int kr = ty + (p<<2);
    t[kr][tx] = wproj[(size_t)(k0+kr)*512 + n0 + tx];
  }
  __syncthreads();
#pragma unroll
  for (int p=0;p<16;p++){
    int nr = ty + (p<<2);
    float v = t[tx][nr];
    _Float16 h = (_Float16)v;
    _Float16 lo = (_Float16)((v - (float)h)*2048.0f);
    Wh[(size_t)(n0+nr)*512 + k0 + tx] = h;
    Wl[(size_t)(n0+nr)*512 + k0 + tx] = lo;
  }
}

// =================== QKV GEMM: x(4096x512) @ w(512x1536) -> Qf/Kf/Khi/V/FI ===================
// 64x128 tile, grid (64,12)=768 blocks = exactly 3 blocks/CU. Per-element fp32
// summation order (kk asc within kc, kc asc) is IDENTICAL to prior rounds.
__global__ __launch_bounds__(256, 3)
void qkv_kernel(const float* __restrict__ x, const float* __restrict__ wqkv,
                const float* __restrict__ bqkv,
                float* __restrict__ Qf, float* __restrict__ Kf,
                _Float16* __restrict__ Khi,
                float* __restrict__ V, float* __restrict__ FI)
{
  __shared__ __align__(16) float Al[32][68];    // [k][m]
  __shared__ __align__(16) float Bl[32][128];   // [k][n]
  const int tid = threadIdx.x;
  const int tx = tid & 15, ty = tid >> 4;
  const int m0 = blockIdx.x * 64, n0 = blockIdx.y * 128;

  float acc[4][8];
#pragma unroll
  for (int i=0;i<4;i++)
#pragma unroll
    for (int j=0;j<8;j++) acc[i][j] = 0.f;

  float4 ra[2], rb[4];
  auto gload = [&](int kc){
#pragma unroll
    for (int p=0;p<2;p++){
      int e = tid + (p<<8);
      int arow = e >> 3, akq = (e & 7) << 2;
      ra[p] = *(const float4*)&x[(size_t)(m0+arow)*512 + kc + akq];
    }
#pragma unroll
    for (int p=0;p<4;p++){
      int e = tid + (p<<8);
      int krow = e >> 5, bnq = (e & 31) << 2;
      rb[p] = *(const float4*)&wqkv[(size_t)(kc+krow)*1536 + n0 + bnq];
    }
  };

  gload(0);
  for (int kc=0; kc<512; kc+=32){
    __syncthreads();
#pragma unroll
    for (int p=0;p<2;p++){
      int e = tid + (p<<8);
      int arow = e>>3, akq = (e&7)<<2;
      Al[akq+0][arow] = ra[p].x;
      Al[akq+1][arow] = ra[p].y;
      Al[akq+2][arow] = ra[p].z;
      Al[akq+3][arow] = ra[p].w;
    }
#pragma unroll
    for (int p=0;p<4;p++){
      int e = tid + (p<<8);
      int krow = e>>5, bnq = (e&31)<<2;
      *(float4*)&Bl[krow][bnq] = rb[p];
    }
    __syncthreads();
    if (kc < 480) gload(kc+32);
#pragma unroll
    for (int kk=0; kk<32; ++kk){
      float a[4], b[8];
      *(float4*)&a[0] = *(const float4*)&Al[kk][ty<<2];
      *(float4*)&b[0] = *(const float4*)&Bl[kk][tx<<2];
      *(float4*)&b[4] = *(const float4*)&Bl[kk][64 + (tx<<2)];
#pragma unroll
      for (int i=0;i<4;i++)
#pragma unroll
        for (int j=0;j<8;j++) acc[i][j] = fmaf(a[i], b[j], acc[i][j]);
    }
  }

  // epilogue: each 64-col group is uniformly one head of Q, K or V (all stores coalesced)
#pragma unroll
  for (int cj=0; cj<2; cj++){
    int nb = n0 + (cj<<6);
    int which = nb >> 9;           // 0:Q 1:K 2:V
    int h = (nb >> 6) & 7;
    float4 bq = *(const float4*)&bqkv[nb + (tx<<2)];
#pragma unroll
    for (int i=0;i<4;i++){
      int m = m0 + (ty<<2) + i;
      int bb = m >> 11, s = m & 2047;
      float4 v4;
      v4.x = acc[i][(cj<<2)+0] + bq.x;
      v4.y = acc[i][(cj<<2)+1] + bq.y;
      v4.z = acc[i][(cj<<2)+2] + bq.z;
      v4.w = acc[i][(cj<<2)+3] + bq.w;
      size_t base = (((size_t)bb*NH_ + h)*S_ + s)*HD_ + (tx<<2);
      if (which == 2){
        *(float4*)&V[base] = v4;
      } else if (which == 0){
        *(float4*)&Qf[base] = v4;
        float fs = v4.x + v4.y + v4.z + v4.w;
#pragma unroll
        for (int st=1; st<16; st<<=1) fs += __shfl_xor(fs, st);
        if (tx == 0)
          FI[((size_t)bb*NH_ + h)*S_ + s] = 1.0f / (1.0f + expf(-fs * (1.0f/64.0f)));
      } else {
        *(float4*)&Kf[base] = v4;
        half4v hv;
        hv[0] = (_Float16)(v4.x * 16.0f);
        hv[1] = (_Float16)(v4.y * 16.0f);
        hv[2] = (_Float16)(v4.z * 16.0f);
        hv[3] = (_Float16)(v4.w * 16.0f);
        *(half4v*)&Khi[base] = hv;
      }
    }
  }
}

// =================== fused attention: two-pass MFMA prune -> exact fp32 selection ===================
#define CE(x,y){ float mx_=fmaxf(x,y), mn_=fminf(x,y); x=mx_; y=mn_; }
#define SORT5(t0,t1,t2,t3,t4) \
    CE(t0,t1) CE(t3,t4) CE(t2,t4) CE(t2,t3) CE(t1,t4) \
    CE(t0,t3) CE(t0,t2) CE(t1,t3) CE(t1,t2)
#define MERGE5(a0,a1,a2,a3,a4,b0,b1,b2,b3,b4) { \
    a0 = fmaxf(a0,b4); a1 = fmaxf(a1,b3); a2 = fmaxf(a2,b2); \
    a3 = fmaxf(a3,b1); a4 = fmaxf(a4,b0); \
    SORT5(a0,a1,a2,a3,a4) }
// insert v into sorted-desc t0..t4 (multiset top-5, 9 ops, unconditional)
#define INS5(t0,t1,t2,t3,t4,v){ \
    float r0_ = fminf(t0, v); t0 = fmaxf(t0, v); \
    float r1_ = fminf(t1, r0_); t1 = fmaxf(t1, r0_); \
    float r2_ = fminf(t2, r1_); t2 = fmaxf(t2, r1_); \
    float r3_ = fminf(t3, r2_); t3 = fmaxf(t3, r2_); \
    t4 = fmaxf(t4, r3_); }

__global__ __launch_bounds__(256, 4)
void attn_kernel(const float* __restrict__ Qf, const float* __restrict__ Kf,
                 const _Float16* __restrict__ Khi,
                 const float* __restrict__ V, const float* __restrict__ FI,
                 float* __restrict__ attn,
                 _Float16* __restrict__ AOh, _Float16* __restrict__ AOl)
{
  __shared__ __align__(16) float qsl[16*64];   // q rows, pre-scaled 0.125
  __shared__ float diag[16][24];               // EXACT window scores
  __shared__ float wtop[4][16][5];             // approx per-wave top5
  __shared__ float tgA[16];                    // approx thr_g
  __shared__ float cmaxW[4][32];               // per-(wave,tile) score max
  __shared__ int   ccnt[16];
  __shared__ int   ccol[16][32];
  __shared__ float cex[16][32];

  const int tid  = threadIdx.x;
  const int w    = tid >> 6, l = tid & 63;
  const int quad = l >> 4, ln = l & 15;
  const int head = blockIdx.x >> 7;
  const int r0   = (blockIdx.x & 127) << 4;
  const int cb   = w << 9;               // wave's 512-col window

  if (tid < 16) ccnt[tid] = 0;

  float* attnh = attn + (size_t)head*S_*S_;

  // ---- zero-fill this block's 16 attn rows (wave w owns rows 4w..4w+3) ----
  {
    const float4 z4 = {0.f,0.f,0.f,0.f};
    float4* zp = (float4*)(attnh + (size_t)(r0 + (w<<2))*S_) + l;
#pragma unroll
    for (int rr=0;rr<4;rr++)
#pragma unroll
      for (int i=0;i<8;i++)
        zp[rr*512 + i*64] = z4;
  }

  // ---- stage q rows (scaled 0.125, exact pow2) ----
  {
    const float4* qg = (const float4*)(Qf + ((size_t)head*S_ + r0)*HD_);
    float4 q4 = qg[tid];
    q4.x *= 0.125f; q4.y *= 0.125f; q4.z *= 0.125f; q4.w *= 0.125f;
    ((float4*)qsl)[tid] = q4;
  }
  __syncthreads();

  // ---- A-fragments (hi plane): A[m=ln][k=quad*8+j (+32)] ----
  half8 a_h0, a_h1;
#pragma unroll
  for (int j=0;j<8;j++){
    a_h0[j] = (_Float16)(qsl[ln*HD_ + quad*8 + j] * 128.0f);
    a_h1[j] = (_Float16)(qsl[ln*HD_ + quad*8 + j + 32] * 128.0f);
  }

  const _Float16* kh = Khi + (size_t)head*S_*HD_;
  const float*    kf = Kf  + (size_t)head*S_*HD_;

  // ---- pass 1: stream tiles, keep per-row top5 in regs + per-tile wave max ----
  float t5[4][5];
#pragma unroll
  for (int g=0;g<4;g++)
#pragma unroll
    for (int k=0;k<5;k++) t5[g][k] = -INFINITY;

#pragma unroll 4
  for (int t=0; t<32; ++t){
    size_t boff = (size_t)(cb + (t<<4) + ln)*HD_ + quad*8;
    half8 bh0 = *(const half8*)(kh + boff);
    half8 bh1 = *(const half8*)(kh + boff + 32);
    f32x4 a4 = {0.f,0.f,0.f,0.f};
    a4 = __builtin_amdgcn_mfma_f32_16x16x32_f16(a_h0, bh0, a4, 0,0,0);
    a4 = __builtin_amdgcn_mfma_f32_16x16x32_f16(a_h1, bh1, a4, 0,0,0);
    float vv[4];
#pragma unroll
    for (int g=0; g<4; ++g){
      vv[g] = a4[g] * 0x1p-11f;
      INS5(t5[g][0],t5[g][1],t5[g][2],t5[g][3],t5[g][4], vv[g])
    }
    float vm = fmaxf(fmaxf(vv[0],vv[1]), fmaxf(vv[2],vv[3]));
#pragma unroll
    for (int st=1; st<64; st<<=1) vm = fmaxf(vm, __shfl_xor(vm, st));
    if (l == 0) cmaxW[w][t] = vm;
  }

  // butterfly-merge top5 across the 16 ln lanes, then stash per-wave
#pragma unroll
  for (int g=0; g<4; ++g){
    float a0=t5[g][0], a1=t5[g][1], a2=t5[g][2], a3=t5[g][3], a4=t5[g][4];
#pragma unroll
    for (int st=1; st<16; st<<=1){
      float b0 = __shfl_xor(a4, st);
      float b1 = __shfl_xor(a3, st);
      float b2 = __shfl_xor(a2, st);
      float b3 = __shfl_xor(a1, st);
      float b4 = __shfl_xor(a0, st);
      MERGE5(a0,a1,a2,a3,a4, b4,b3,b2,b1,b0)
    }
    if (ln == 0){
      int row = (quad<<2) + g;
      wtop[w][row][0]=a0; wtop[w][row][1]=a1; wtop[w][row][2]=a2;
      wtop[w][row][3]=a3; wtop[w][row][4]=a4;
    }
  }
  __syncthreads();

  if (tid < 16){
    float m5[5] = {-INFINITY,-INFINITY,-INFINITY,-INFINITY,-INFINITY};
    for (int ww=0; ww<4; ww++)
      for (int k=0;k<5;k++){
        float v = wtop[ww][tid][k];
        float b0 = fminf(m5[0], v); m5[0] = fmaxf(m5[0], v);
        float b1 = fminf(m5[1], b0); m5[1] = fmaxf(m5[1], b0);
        float b2 = fminf(m5[2], b1); m5[2] = fmaxf(m5[2], b1);
        float b3 = fminf(m5[3], b2); m5[3] = fmaxf(m5[3], b2);
        m5[4] = fmaxf(m5[4], b3);
      }
    tgA[tid] = m5[4];
  }
  __syncthreads();

  // ---- pass 2: recompute ONLY tiles whose wave-max can reach a threshold ----
  {
    float thr[4];
#pragma unroll
    for (int g=0;g<4;g++) thr[g] = tgA[(quad<<2)+g] - MARGIN;
    float mthr = fminf(fminf(thr[0],thr[1]), fminf(thr[2],thr[3]));
    mthr = fminf(mthr, __shfl_xor(mthr, 16));
    mthr = fminf(mthr, __shfl_xor(mthr, 32));   // wave-uniform min over 16 rows
#pragma unroll 4
    for (int t=0; t<32; ++t){
      if (cmaxW[w][t] >= mthr){
        size_t boff = (size_t)(cb + (t<<4) + ln)*HD_ + quad*8;
        half8 bh0 = *(const half8*)(kh + boff);
        half8 bh1 = *(const half8*)(kh + boff + 32);
        f32x4 a4 = {0.f,0.f,0.f,0.f};
        a4 = __builtin_amdgcn_mfma_f32_16x16x32_f16(a_h0, bh0, a4, 0,0,0);
        a4 = __builtin_amdgcn_mfma_f32_16x16x32_f16(a_h1, bh1, a4, 0,0,0);
#pragma unroll
        for (int g=0; g<4; ++g){
          float v = a4[g] * 0x1p-11f;
          if (v >= thr[g]){
            int row = (quad<<2) + g;
            int c = cb + (t<<4) + ln;
            int slot = atomicAdd(&ccnt[row], 1);
            if (slot < 32) ccol[row][slot] = c;
          }
        }
      }
    }
  }

  // ---- EXACT diag (window cols [Lo, Lo+24)) via scalar fp32 dots ----
  const int Lo = (r0 >= 4) ? (r0 - 4) : 0;
  {
    int row = tid >> 4, j = tid & 15;
    int c0 = Lo + j;
    if (c0 < S_) diag[row][j] = dot64(qsl + row*HD_, kf + (size_t)c0*HD_);
    if (j < 8){
      int c1 = Lo + 16 + j;
      if (c1 < S_) diag[row][16+j] = dot64(qsl + row*HD_, kf + (size_t)c1*HD_);
    }
  }
  __syncthreads();

  // ---- EXACT rescore of candidates ----
  {
    int row = tid >> 4, j = tid & 15;
    int n = ccnt[row]; if (n > 32) n = 32;
    if (j < n)      cex[row][j]    = dot64(qsl + row*HD_, kf + (size_t)ccol[row][j]*HD_);
    if (j + 16 < n) cex[row][j+16] = dot64(qsl + row*HD_, kf + (size_t)ccol[row][j+16]*HD_);
  }
  __syncthreads();

  // ---- exact selection + softmax (serial per row; all values exact fp32) ----
  if (tid < 16){
    int n = ccnt[tid]; if (n > 32) n = 32;
    float m5[5] = {-INFINITY,-INFINITY,-INFINITY,-INFINITY,-INFINITY};
    for (int i=0;i<n;i++){
      float v = cex[tid][i];
      float b0 = fminf(m5[0], v); m5[0] = fmaxf(m5[0], v);
      float b1 = fminf(m5[1], b0); m5[1] = fmaxf(m5[1], b0);
      float b2 = fminf(m5[2], b1); m5[2] = fmaxf(m5[2], b1);
      float b3 = fminf(m5[3], b2); m5[3] = fmaxf(m5[3], b2);
      m5[4] = fmaxf(m5[4], b3);
    }
    float tg = m5[4], mx = m5[0];
    int R = r0 + tid;
    int b = R & ~1; if (b > 2044) b = 2044;
    float tb = snd_smallest4(diag[tid][b-Lo], diag[tid][b+1-Lo],
                             diag[tid][b+2-Lo], diag[tid][b+3-Lo]);
    float ta = -INFINITY;
    if (b >= 2 && (R - b) <= 1){
      int a0i = b - 2;
      ta = snd_smallest4(diag[tid][a0i-Lo], diag[tid][a0i+1-Lo],
                         diag[tid][a0i+2-Lo], diag[tid][a0i+3-Lo]);
    }
    float Z = 0.f; int k = 0;
    for (int i=0;i<n;i++){
      float s = cex[tid][i]; int c = ccol[tid][i];
      bool inb = (unsigned)(c - b) < 4u;
      bool ina = (unsigned)(c - (b-2)) < 2u;
      float lt = inb ? tb : (ina ? ta : -INFINITY);
      if (s >= tg && s >= lt){
        float p = expf(s - mx);
        Z += p;
        ccol[tid][k] = c; cex[tid][k] = p; k++;
      }
    }
    float inv = 1.0f / Z;
    for (int i=0;i<k;i++) cex[tid][i] *= inv;   // normalized attn weights
    ccnt[tid] = k;
  }
  __syncthreads();

  // ---- scatter normalized nonzeros (wave w owns rows 4w..4w+3) ----
#pragma unroll
  for (int rr=0;rr<4;rr++){
    int r = (w<<2) + rr;
    size_t rowb = (size_t)(r0 + r) * S_;
    int n = ccnt[r];
    for (int s2 = l; s2 < n; s2 += 64)
      attnh[rowb + ccol[r][s2]] = cex[r][s2];
  }

  // ---- sparse out = sum attn * v * fi -> AO fp16 hi/lo planes ----
  const float* vh  = V  + (size_t)head*S_*HD_;
  const float* fih = FI + (size_t)head*S_;
  const int bb = head >> 3, hh = head & 7;
#pragma unroll
  for (int rr=0;rr<4;rr++){
    int r = (w<<2) + rr;
    int n = ccnt[r];
    float o = 0.f;
    for (int i=0;i<n;i++){
      int c = ccol[r][i];
      float av = cex[r][i] * fih[c];
      o = fmaf(av, vh[(size_t)c*HD_ + l], o);
    }
    size_t oidx = (((size_t)bb*S_ + (r0+r))*NH_ + hh)*HD_ + l;
    _Float16 oh = (_Float16)o;
    _Float16 ol = (_Float16)((o - (float)oh) * 2048.0f);
    AOh[oidx] = oh;
    AOl[oidx] = ol;
  }
}
#undef CE
#undef SORT5
#undef MERGE5
#undef INS5

// =================== proj GEMM via fp16-split MFMA: out = AO @ w_proj + b ===================
__global__ __launch_bounds__(256)
void proj_kernel(const _Float16* __restrict__ AOh, const _Float16* __restrict__ AOl,
                 const _Float16* __restrict__ Wh, const _Float16* __restrict__ Wl,
                 const float* __restrict__ bproj, float* __restrict__ outp)
{
  const int tid = threadIdx.x;
  const int w = tid >> 6, l = tid & 63;
  const int quad = l >> 4, ln = l & 15;
  const int r0 = blockIdx.x << 4;
  const int nb = (blockIdx.y << 8) + (w << 6);

  f32x4 accA[4], accB[4];
#pragma unroll
  for (int nt=0;nt<4;nt++){
    accA[nt] = (f32x4){0.f,0.f,0.f,0.f};
    accB[nt] = (f32x4){0.f,0.f,0.f,0.f};
  }

  const _Float16* ah = AOh + (size_t)(r0+ln)*512 + quad*8;
  const _Float16* al = AOl + (size_t)(r0+ln)*512 + quad*8;

#pragma unroll 4
  for (int kc=0; kc<16; ++kc){
    half8 a_h = *(const half8*)(ah + (kc<<5));
    half8 a_l = *(const half8*)(al + (kc<<5));
#pragma unroll
    for (int nt=0; nt<4; ++nt){
      size_t bo = (size_t)(nb + (nt<<4) + ln)*512 + (kc<<5) + quad*8;
      half8 b_h = *(const half8*)(Wh + bo);
      half8 b_l = *(const half8*)(Wl + bo);
      accA[nt] = __builtin_amdgcn_mfma_f32_16x16x32_f16(a_h, b_h, accA[nt], 0,0,0);
      accB[nt] = __builtin_amdgcn_mfma_f32_16x16x32_f16(a_h, b_l, accB[nt], 0,0,0);
      accB[nt] = __builtin_amdgcn_mfma_f32_16x16x32_f16(a_l, b_h, accB[nt], 0,0,0);
    }
  }

#pragma unroll
  for (int nt=0; nt<4; ++nt){
    int n = nb + (nt<<4) + ln;
    float bias = bproj[n];
#pragma unroll
    for (int g=0; g<4; ++g){
      int m = r0 + (quad<<2) + g;
      outp[(size_t)m*512 + n] = accA[nt][g] + accB[nt][g]*0x1p-11f + bias;
    }
  }
}

extern "C" void kernel_launch(void* const* d_in, const int* in_sizes, int n_in,
                              void* d_out, int out_size, void* d_ws, size_t ws_size,
                              hipStream_t stream)
{
  const float* x     = (const float*)d_in[0];
  const float* wqkv  = (const float*)d_in[1];
  const float* bqkv  = (const float*)d_in[2];
  const float* wproj = (const float*)d_in[3];
  const float* bproj = (const float*)d_in[4];

  float* out  = (float*)d_out;               // (2,2048,512)
  float* attn = out + 2097152;               // (2,8,2048,2048)

  // ws layout: V, FI, Qf, Kf (fp32) | Khi, AOh, AOl, Wh, Wl (fp16)  ~= 39 MB
  float* ws = (float*)d_ws;
  float* V   = ws;
  float* FI  = V  + 2097152;
  float* Qf  = FI + 32768;
  float* Kf  = Qf + 2097152;
  _Float16* Khi = (_Float16*)(Kf + 2097152);
  _Float16* AOh = Khi + 2097152;
  _Float16* AOl = AOh + 2097152;
  _Float16* Wh  = AOl + 2097152;
  _Float16* Wl  = Wh  + 262144;

  wprep_kernel<<<64,          256, 0, stream>>>(wproj, Wh, Wl);
  qkv_kernel  <<<dim3(64,12), 256, 0, stream>>>(x, wqkv, bqkv, Qf, Kf, Khi, V, FI);
  attn_kernel <<<2048,        256, 0, stream>>>(Qf, Kf, Khi, V, FI, attn, AOh, AOl);
  proj_kernel <<<dim3(256,2), 256, 0, stream>>>(AOh, AOl, Wh, Wl, bproj, out);
}

// Round 10
// 589.436 us; speedup vs baseline: 1.0284x; 1.0284x over previous
//
#include <hip/hip_runtime.h>

#define S_  2048
#define HD_ 64
#define NH_ 8
#define MARGIN 4e-3f
#define QSTR 68   // qsl row stride: 68%32=4 banks -> 4 concurrent rows conflict-free

typedef _Float16 half8 __attribute__((ext_vector_type(8)));
typedef _Float16 half4v __attribute__((ext_vector_type(4)));
typedef float    f32x4 __attribute__((ext_vector_type(4)));

// 2nd smallest of 4 == 3rd largest counting multiplicity (matches top_k[-1] + >= semantics)
__device__ __forceinline__ float snd_smallest4(float a, float b, float c, float d){
  float lo1 = fminf(a,b), hi1 = fmaxf(a,b);
  float lo2 = fminf(c,d), hi2 = fmaxf(c,d);
  return fminf(fmaxf(lo1,lo2), fminf(hi1,hi2));
}

// exact fp32 dot, R3-validated summation order (d ascending, paired FMA chain)
// qrow is pre-scaled by 0.125 -> result = q.k/8
__device__ __forceinline__ float dot64(const float* __restrict__ qrow,
                                       const float* __restrict__ kcol){
  float acc = 0.f;
#pragma unroll
  for (int dp=0; dp<32; ++dp){
    float2 k2 = *(const float2*)(kcol + 2*dp);
    acc = fmaf(qrow[2*dp+1], k2.y, fmaf(qrow[2*dp], k2.x, acc));
  }
  return acc;
}

// =================== w_proj transpose + fp16 2-plane split: Wh/Wl[n][k] ===================
__global__ __launch_bounds__(256)
void wprep_kernel(const float* __restrict__ wproj,
                  _Float16* __restrict__ Wh, _Float16* __restrict__ Wl)
{
  __shared__ float t[64][65];
  const int k0 = (blockIdx.x >> 3) << 6;
  const int n0 = (blockIdx.x & 7) << 6;
  const int tx = threadIdx.x & 63, ty = threadIdx.x >> 6;
#pragma unroll
  for (int p=0;p<16;p++){
    int kr = ty + (p<<2);
    t[kr][tx] = wproj[(size_t)(k0+kr)*512 + n0 + tx];
  }
  __syncthreads();
#pragma unroll
  for (int p=0;p<16;p++){
    int nr = ty + (p<<2);
    float v = t[tx][nr];
    _Float16 h = (_Float16)v;
    _Float16 lo = (_Float16)((v - (float)h)*2048.0f);
    Wh[(size_t)(n0+nr)*512 + k0 + tx] = h;
    Wl[(size_t)(n0+nr)*512 + k0 + tx] = lo;
  }
}

// =================== QKV GEMM: x(4096x512) @ w(512x1536) -> Qf/Kf/Khi/V/FI ===================
// 64x128 tile, grid (64,12)=768 blocks = exactly 3 blocks/CU. Per-element fp32
// summation order (kk asc within kc, kc asc) is IDENTICAL to prior rounds.
__global__ __launch_bounds__(256, 3)
void qkv_kernel(const float* __restrict__ x, const float* __restrict__ wqkv,
                const float* __restrict__ bqkv,
                float* __restrict__ Qf, float* __restrict__ Kf,
                _Float16* __restrict__ Khi,
                float* __restrict__ V, float* __restrict__ FI)
{
  __shared__ __align__(16) float Al[32][68];    // [k][m]
  __shared__ __align__(16) float Bl[32][128];   // [k][n]
  const int tid = threadIdx.x;
  const int tx = tid & 15, ty = tid >> 4;
  const int m0 = blockIdx.x * 64, n0 = blockIdx.y * 128;

  float acc[4][8];
#pragma unroll
  for (int i=0;i<4;i++)
#pragma unroll
    for (int j=0;j<8;j++) acc[i][j] = 0.f;

  float4 ra[2], rb[4];
  auto gload = [&](int kc){
#pragma unroll
    for (int p=0;p<2;p++){
      int e = tid + (p<<8);
      int arow = e >> 3, akq = (e & 7) << 2;
      ra[p] = *(const float4*)&x[(size_t)(m0+arow)*512 + kc + akq];
    }
#pragma unroll
    for (int p=0;p<4;p++){
      int e = tid + (p<<8);
      int krow = e >> 5, bnq = (e & 31) << 2;
      rb[p] = *(const float4*)&wqkv[(size_t)(kc+krow)*1536 + n0 + bnq];
    }
  };

  gload(0);
  for (int kc=0; kc<512; kc+=32){
    __syncthreads();
#pragma unroll
    for (int p=0;p<2;p++){
      int e = tid + (p<<8);
      int arow = e>>3, akq = (e&7)<<2;
      Al[akq+0][arow] = ra[p].x;
      Al[akq+1][arow] = ra[p].y;
      Al[akq+2][arow] = ra[p].z;
      Al[akq+3][arow] = ra[p].w;
    }
#pragma unroll
    for (int p=0;p<4;p++){
      int e = tid + (p<<8);
      int krow = e>>5, bnq = (e&31)<<2;
      *(float4*)&Bl[krow][bnq] = rb[p];
    }
    __syncthreads();
    if (kc < 480) gload(kc+32);
#pragma unroll
    for (int kk=0; kk<32; ++kk){
      float a[4], b[8];
      *(float4*)&a[0] = *(const float4*)&Al[kk][ty<<2];
      *(float4*)&b[0] = *(const float4*)&Bl[kk][tx<<2];
      *(float4*)&b[4] = *(const float4*)&Bl[kk][64 + (tx<<2)];
#pragma unroll
      for (int i=0;i<4;i++)
#pragma unroll
        for (int j=0;j<8;j++) acc[i][j] = fmaf(a[i], b[j], acc[i][j]);
    }
  }

  // epilogue: each 64-col group is uniformly one head of Q, K or V (all stores coalesced)
#pragma unroll
  for (int cj=0; cj<2; cj++){
    int nb = n0 + (cj<<6);
    int which = nb >> 9;           // 0:Q 1:K 2:V
    int h = (nb >> 6) & 7;
    float4 bq = *(const float4*)&bqkv[nb + (tx<<2)];
#pragma unroll
    for (int i=0;i<4;i++){
      int m = m0 + (ty<<2) + i;
      int bb = m >> 11, s = m & 2047;
      float4 v4;
      v4.x = acc[i][(cj<<2)+0] + bq.x;
      v4.y = acc[i][(cj<<2)+1] + bq.y;
      v4.z = acc[i][(cj<<2)+2] + bq.z;
      v4.w = acc[i][(cj<<2)+3] + bq.w;
      size_t base = (((size_t)bb*NH_ + h)*S_ + s)*HD_ + (tx<<2);
      if (which == 2){
        *(float4*)&V[base] = v4;
      } else if (which == 0){
        *(float4*)&Qf[base] = v4;
        float fs = v4.x + v4.y + v4.z + v4.w;
#pragma unroll
        for (int st=1; st<16; st<<=1) fs += __shfl_xor(fs, st);
        if (tx == 0)
          FI[((size_t)bb*NH_ + h)*S_ + s] = 1.0f / (1.0f + expf(-fs * (1.0f/64.0f)));
      } else {
        *(float4*)&Kf[base] = v4;
        half4v hv;
        hv[0] = (_Float16)(v4.x * 16.0f);
        hv[1] = (_Float16)(v4.y * 16.0f);
        hv[2] = (_Float16)(v4.z * 16.0f);
        hv[3] = (_Float16)(v4.w * 16.0f);
        *(half4v*)&Khi[base] = hv;
      }
    }
  }
}

// =================== fused attention: two-pass MFMA prune -> exact fp32 selection ===================
#define CE(x,y){ float mx_=fmaxf(x,y), mn_=fminf(x,y); x=mx_; y=mn_; }
#define SORT5(t0,t1,t2,t3,t4) \
    CE(t0,t1) CE(t3,t4) CE(t2,t4) CE(t2,t3) CE(t1,t4) \
    CE(t0,t3) CE(t0,t2) CE(t1,t3) CE(t1,t2)
#define MERGE5(a0,a1,a2,a3,a4,b0,b1,b2,b3,b4) { \
    a0 = fmaxf(a0,b4); a1 = fmaxf(a1,b3); a2 = fmaxf(a2,b2); \
    a3 = fmaxf(a3,b1); a4 = fmaxf(a4,b0); \
    SORT5(a0,a1,a2,a3,a4) }
// insert v into sorted-desc t0..t4 (multiset top-5, 9 ops, unconditional)
#define INS5(t0,t1,t2,t3,t4,v){ \
    float r0_ = fminf(t0, v); t0 = fmaxf(t0, v); \
    float r1_ = fminf(t1, r0_); t1 = fmaxf(t1, r0_); \
    float r2_ = fminf(t2, r1_); t2 = fmaxf(t2, r1_); \
    float r3_ = fminf(t3, r2_); t3 = fmaxf(t3, r2_); \
    t4 = fmaxf(t4, r3_); }

__global__ __launch_bounds__(256, 8)
void attn_kernel(const float* __restrict__ Qf, const float* __restrict__ Kf,
                 const _Float16* __restrict__ Khi,
                 const float* __restrict__ V, const float* __restrict__ FI,
                 float* __restrict__ attn,
                 _Float16* __restrict__ AOh, _Float16* __restrict__ AOl)
{
  __shared__ __align__(16) float qsl[16*QSTR]; // q rows (stride 68), pre-scaled 0.125
  __shared__ float diag[16][24];               // EXACT window scores
  __shared__ float wtop[4][16][5];             // approx per-wave top5
  __shared__ float tgA[16];                    // approx thr_g
  __shared__ int   ccnt[16];
  __shared__ int   ccol[16][32];
  __shared__ float cex[16][32];

  const int tid  = threadIdx.x;
  const int w    = tid >> 6, l = tid & 63;
  const int quad = l >> 4, ln = l & 15;
  const int head = blockIdx.x >> 7;
  const int r0   = (blockIdx.x & 127) << 4;
  const int cb   = w << 9;               // wave's 512-col window

  if (tid < 16) ccnt[tid] = 0;

  float* attnh = attn + (size_t)head*S_*S_;

  // ---- zero-fill this block's 16 attn rows (wave w owns rows 4w..4w+3) ----
  {
    const float4 z4 = {0.f,0.f,0.f,0.f};
    float4* zp = (float4*)(attnh + (size_t)(r0 + (w<<2))*S_) + l;
#pragma unroll
    for (int rr=0;rr<4;rr++)
#pragma unroll
      for (int i=0;i<8;i++)
        zp[rr*512 + i*64] = z4;
  }

  // ---- stage q rows (scaled 0.125, exact pow2) into padded LDS ----
  {
    const float4* qg = (const float4*)(Qf + ((size_t)head*S_ + r0)*HD_);
    float4 q4 = qg[tid];
    q4.x *= 0.125f; q4.y *= 0.125f; q4.z *= 0.125f; q4.w *= 0.125f;
    int row = tid >> 4, c4 = (tid & 15) << 2;
    *(float4*)&qsl[row*QSTR + c4] = q4;
  }
  __syncthreads();

  // ---- A-fragments (hi plane): A[m=ln][k=quad*8+j (+32)] ----
  half8 a_h0, a_h1;
#pragma unroll
  for (int j=0;j<8;j++){
    a_h0[j] = (_Float16)(qsl[ln*QSTR + quad*8 + j] * 128.0f);
    a_h1[j] = (_Float16)(qsl[ln*QSTR + quad*8 + j + 32] * 128.0f);
  }

  const _Float16* kh = Khi + (size_t)head*S_*HD_;
  const float*    kf = Kf  + (size_t)head*S_*HD_;

  // ---- pass 1: stream tiles, keep per-row top5 in regs (no score caching) ----
  float t5[4][5];
#pragma unroll
  for (int g=0;g<4;g++)
#pragma unroll
    for (int k=0;k<5;k++) t5[g][k] = -INFINITY;

#pragma unroll 4
  for (int t=0; t<32; ++t){
    size_t boff = (size_t)(cb + (t<<4) + ln)*HD_ + quad*8;
    half8 bh0 = *(const half8*)(kh + boff);
    half8 bh1 = *(const half8*)(kh + boff + 32);
    f32x4 a4 = {0.f,0.f,0.f,0.f};
    a4 = __builtin_amdgcn_mfma_f32_16x16x32_f16(a_h0, bh0, a4, 0,0,0);
    a4 = __builtin_amdgcn_mfma_f32_16x16x32_f16(a_h1, bh1, a4, 0,0,0);
#pragma unroll
    for (int g=0; g<4; ++g){
      float v = a4[g] * 0x1p-11f;
      INS5(t5[g][0],t5[g][1],t5[g][2],t5[g][3],t5[g][4], v)
    }
  }

  // butterfly-merge top5 across the 16 ln lanes, then stash per-wave
#pragma unroll
  for (int g=0; g<4; ++g){
    float a0=t5[g][0], a1=t5[g][1], a2=t5[g][2], a3=t5[g][3], a4=t5[g][4];
#pragma unroll
    for (int st=1; st<16; st<<=1){
      float b0 = __shfl_xor(a4, st);
      float b1 = __shfl_xor(a3, st);
      float b2 = __shfl_xor(a2, st);
      float b3 = __shfl_xor(a1, st);
      float b4 = __shfl_xor(a0, st);
      MERGE5(a0,a1,a2,a3,a4, b4,b3,b2,b1,b0)
    }
    if (ln == 0){
      int row = (quad<<2) + g;
      wtop[w][row][0]=a0; wtop[w][row][1]=a1; wtop[w][row][2]=a2;
      wtop[w][row][3]=a3; wtop[w][row][4]=a4;
    }
  }
  __syncthreads();

  if (tid < 16){
    float m5[5] = {-INFINITY,-INFINITY,-INFINITY,-INFINITY,-INFINITY};
    for (int ww=0; ww<4; ww++)
      for (int k=0;k<5;k++){
        float v = wtop[ww][tid][k];
        float b0 = fminf(m5[0], v); m5[0] = fmaxf(m5[0], v);
        float b1 = fminf(m5[1], b0); m5[1] = fmaxf(m5[1], b0);
        float b2 = fminf(m5[2], b1); m5[2] = fmaxf(m5[2], b1);
        float b3 = fminf(m5[3], b2); m5[3] = fmaxf(m5[3], b2);
        m5[4] = fmaxf(m5[4], b3);
      }
    tgA[tid] = m5[4];
  }
  __syncthreads();

  // ---- pass 2: recompute tiles (bit-identical) + gather candidates ----
  {
    float thr[4];
#pragma unroll
    for (int g=0;g<4;g++) thr[g] = tgA[(quad<<2)+g] - MARGIN;
#pragma unroll 4
    for (int t=0; t<32; ++t){
      size_t boff = (size_t)(cb + (t<<4) + ln)*HD_ + quad*8;
      half8 bh0 = *(const half8*)(kh + boff);
      half8 bh1 = *(const half8*)(kh + boff + 32);
      f32x4 a4 = {0.f,0.f,0.f,0.f};
      a4 = __builtin_amdgcn_mfma_f32_16x16x32_f16(a_h0, bh0, a4, 0,0,0);
      a4 = __builtin_amdgcn_mfma_f32_16x16x32_f16(a_h1, bh1, a4, 0,0,0);
#pragma unroll
      for (int g=0; g<4; ++g){
        float v = a4[g] * 0x1p-11f;
        if (v >= thr[g]){
          int row = (quad<<2) + g;
          int c = cb + (t<<4) + ln;
          int slot = atomicAdd(&ccnt[row], 1);
          if (slot < 32) ccol[row][slot] = c;
        }
      }
    }
  }

  // ---- EXACT diag (window cols [Lo, Lo+24)) via scalar fp32 dots ----
  const int Lo = (r0 >= 4) ? (r0 - 4) : 0;
  {
    int row = tid >> 4, j = tid & 15;
    int c0 = Lo + j;
    if (c0 < S_) diag[row][j] = dot64(qsl + row*QSTR, kf + (size_t)c0*HD_);
    if (j < 8){
      int c1 = Lo + 16 + j;
      if (c1 < S_) diag[row][16+j] = dot64(qsl + row*QSTR, kf + (size_t)c1*HD_);
    }
  }
  __syncthreads();

  // ---- EXACT rescore of candidates ----
  {
    int row = tid >> 4, j = tid & 15;
    int n = ccnt[row]; if (n > 32) n = 32;
    if (j < n)      cex[row][j]    = dot64(qsl + row*QSTR, kf + (size_t)ccol[row][j]*HD_);
    if (j + 16 < n) cex[row][j+16] = dot64(qsl + row*QSTR, kf + (size_t)ccol[row][j+16]*HD_);
  }
  __syncthreads();

  // ---- exact selection + softmax (serial per row; all values exact fp32) ----
  if (tid < 16){
    int n = ccnt[tid]; if (n > 32) n = 32;
    float m5[5] = {-INFINITY,-INFINITY,-INFINITY,-INFINITY,-INFINITY};
    for (int i=0;i<n;i++){
      float v = cex[tid][i];
      float b0 = fminf(m5[0], v); m5[0] = fmaxf(m5[0], v);
      float b1 = fminf(m5[1], b0); m5[1] = fmaxf(m5[1], b0);
      float b2 = fminf(m5[2], b1); m5[2] = fmaxf(m5[2], b1);
      float b3 = fminf(m5[3], b2); m5[3] = fmaxf(m5[3], b2);
      m5[4] = fmaxf(m5[4], b3);
    }
    float tg = m5[4], mx = m5[0];
    int R = r0 + tid;
    int b = R & ~1; if (b > 2044) b = 2044;
    float tb = snd_smallest4(diag[tid][b-Lo], diag[tid][b+1-Lo],
                             diag[tid][b+2-Lo], diag[tid][b+3-Lo]);
    float ta = -INFINITY;
    if (b >= 2 && (R - b) <= 1){
      int a0i = b - 2;
      ta = snd_smallest4(diag[tid][a0i-Lo], diag[tid][a0i+1-Lo],
                         diag[tid][a0i+2-Lo], diag[tid][a0i+3-Lo]);
    }
    float Z = 0.f; int k = 0;
    for (int i=0;i<n;i++){
      float s = cex[tid][i]; int c = ccol[tid][i];
      bool inb = (unsigned)(c - b) < 4u;
      bool ina = (unsigned)(c - (b-2)) < 2u;
      float lt = inb ? tb : (ina ? ta : -INFINITY);
      if (s >= tg && s >= lt){
        float p = expf(s - mx);
        Z += p;
        ccol[tid][k] = c; cex[tid][k] = p; k++;
      }
    }
    float inv = 1.0f / Z;
    for (int i=0;i<k;i++) cex[tid][i] *= inv;   // normalized attn weights
    ccnt[tid] = k;
  }
  __syncthreads();

  // ---- scatter normalized nonzeros (wave w owns rows 4w..4w+3) ----
#pragma unroll
  for (int rr=0;rr<4;rr++){
    int r = (w<<2) + rr;
    size_t rowb = (size_t)(r0 + r) * S_;
    int n = ccnt[r];
    for (int s2 = l; s2 < n; s2 += 64)
      attnh[rowb + ccol[r][s2]] = cex[r][s2];
  }

  // ---- sparse out = sum attn * v * fi -> AO fp16 hi/lo planes ----
  const float* vh  = V  + (size_t)head*S_*HD_;
  const float* fih = FI + (size_t)head*S_;
  const int bb = head >> 3, hh = head & 7;
#pragma unroll
  for (int rr=0;rr<4;rr++){
    int r = (w<<2) + rr;
    int n = ccnt[r];
    float o = 0.f;
    for (int i=0;i<n;i++){
      int c = ccol[r][i];
      float av = cex[r][i] * fih[c];
      o = fmaf(av, vh[(size_t)c*HD_ + l], o);
    }
    size_t oidx = (((size_t)bb*S_ + (r0+r))*NH_ + hh)*HD_ + l;
    _Float16 oh = (_Float16)o;
    _Float16 ol = (_Float16)((o - (float)oh) * 2048.0f);
    AOh[oidx] = oh;
    AOl[oidx] = ol;
  }
}
#undef CE
#undef SORT5
#undef MERGE5
#undef INS5

// =================== proj GEMM via fp16-split MFMA: out = AO @ w_proj + b ===================
__global__ __launch_bounds__(256)
void proj_kernel(const _Float16* __restrict__ AOh, const _Float16* __restrict__ AOl,
                 const _Float16* __restrict__ Wh, const _Float16* __restrict__ Wl,
                 const float* __restrict__ bproj, float* __restrict__ outp)
{
  const int tid = threadIdx.x;
  const int w = tid >> 6, l = tid & 63;
  const int quad = l >> 4, ln = l & 15;
  const int r0 = blockIdx.x << 4;
  const int nb = (blockIdx.y << 8) + (w << 6);

  f32x4 accA[4], accB[4];
#pragma unroll
  for (int nt=0;nt<4;nt++){
    accA[nt] = (f32x4){0.f,0.f,0.f,0.f};
    accB[nt] = (f32x4){0.f,0.f,0.f,0.f};
  }

  const _Float16* ah = AOh + (size_t)(r0+ln)*512 + quad*8;
  const _Float16* al = AOl + (size_t)(r0+ln)*512 + quad*8;

#pragma unroll 4
  for (int kc=0; kc<16; ++kc){
    half8 a_h = *(const half8*)(ah + (kc<<5));
    half8 a_l = *(const half8*)(al + (kc<<5));
#pragma unroll
    for (int nt=0; nt<4; ++nt){
      size_t bo = (size_t)(nb + (nt<<4) + ln)*512 + (kc<<5) + quad*8;
      half8 b_h = *(const half8*)(Wh + bo);
      half8 b_l = *(const half8*)(Wl + bo);
      accA[nt] = __builtin_amdgcn_mfma_f32_16x16x32_f16(a_h, b_h, accA[nt], 0,0,0);
      accB[nt] = __builtin_amdgcn_mfma_f32_16x16x32_f16(a_h, b_l, accB[nt], 0,0,0);
      accB[nt] = __builtin_amdgcn_mfma_f32_16x16x32_f16(a_l, b_h, accB[nt], 0,0,0);
    }
  }

#pragma unroll
  for (int nt=0; nt<4; ++nt){
    int n = nb + (nt<<4) + ln;
    float bias = bproj[n];
#pragma unroll
    for (int g=0; g<4; ++g){
      int m = r0 + (quad<<2) + g;
      outp[(size_t)m*512 + n] = accA[nt][g] + accB[nt][g]*0x1p-11f + bias;
    }
  }
}

extern "C" void kernel_launch(void* const* d_in, const int* in_sizes, int n_in,
                              void* d_out, int out_size, void* d_ws, size_t ws_size,
                              hipStream_t stream)
{
  const float* x     = (const float*)d_in[0];
  const float* wqkv  = (const float*)d_in[1];
  const float* bqkv  = (const float*)d_in[2];
  const float* wproj = (const float*)d_in[3];
  const float* bproj = (const float*)d_in[4];

  float* out  = (float*)d_out;               // (2,2048,512)
  float* attn = out + 2097152;               // (2,8,2048,2048)

  // ws layout: V, FI, Qf, Kf (fp32) | Khi, AOh, AOl, Wh, Wl (fp16)  ~= 39 MB
  float* ws = (float*)d_ws;
  float* V   = ws;
  float* FI  = V  + 2097152;
  float* Qf  = FI + 32768;
  float* Kf  = Qf + 2097152;
  _Float16* Khi = (_Float16*)(Kf + 2097152);
  _Float16* AOh = Khi + 2097152;
  _Float16* AOl = AOh + 2097152;
  _Float16* Wh  = AOl + 2097152;
  _Float16* Wl  = Wh  + 262144;

  wprep_kernel<<<64,          256, 0, stream>>>(wproj, Wh, Wl);
  qkv_kernel  <<<dim3(64,12), 256, 0, stream>>>(x, wqkv, bqkv, Qf, Kf, Khi, V, FI);
  attn_kernel <<<2048,        256, 0, stream>>>(Qf, Kf, Khi, V, FI, attn, AOh, AOl);
  proj_kernel <<<dim3(256,2), 256, 0, stream>>>(AOh, AOl, Wh, Wl, bproj, out);
}